// Round 2
// baseline (36635.999 us; speedup 1.0000x reference)
//
#include <hip/hip_runtime.h>

#define H_  1024
#define B_  8
#define T_  2048
#define V_  256
#define NWG 256
#define NTH 256

__device__ __forceinline__ float agload(const float* p) {
  return __hip_atomic_load(p, __ATOMIC_RELAXED, __HIP_MEMORY_SCOPE_AGENT);
}
__device__ __forceinline__ void agstore(float* p, float v) {
  __hip_atomic_store(p, v, __ATOMIC_RELAXED, __HIP_MEMORY_SCOPE_AGENT);
}

__global__ __launch_bounds__(NTH, 1)
void charrnn_lstm(const int* __restrict__ Xs, const int* __restrict__ ys,
                  const float* __restrict__ W_ih, const float* __restrict__ W_hh,
                  const float* __restrict__ b_ih, const float* __restrict__ b_hh,
                  const float* __restrict__ W1, const float* __restrict__ b1,
                  float* __restrict__ out, int* __restrict__ bar, float* __restrict__ hg)
{
  // LDS total = 32768 + 16384 + 4096 + 1024 + 512 + 128 + 64 + 32 = 55008 B (<64KB)
  // W_hh slice lives in 64 VGPRs/thread instead of LDS (round-1 fix: 121KB LDS
  // exceeded the per-WG limit -> cooperative launch silently failed).
  __shared__ float hstage[B_][H_];
  __shared__ float Wis[16][V_];
  __shared__ float stash[H_];
  __shared__ float logits_s[V_];
  __shared__ float gates_s[16][8];
  __shared__ float c_s[4][8];
  __shared__ float bias_s[16];
  __shared__ int   xbuf[8];

  const int wg   = blockIdx.x;
  const int tid  = threadIdx.x;
  const int b_g  = wg & 7;    // batch whose loss this WG computes
  const int slot = wg >> 3;   // t%32 slot this WG stashes
  const int row  = tid >> 4;  // 0..15 : local gate-row (gate*4 + jj)
  const int seg  = tid & 15;  // 0..15 : k-segment

  // ---- W_hh slice -> registers: thread (row,seg) needs exactly these 64 floats ----
  const int rg = (row >> 2) * H_ + wg * 4 + (row & 3);   // global W_hh/W_ih row
  float4 wreg[16];
  #pragma unroll
  for (int q = 0; q < 16; ++q)
    wreg[q] = *(const float4*)&W_hh[(size_t)rg * H_ + seg * 4 + q * 64];

  // ---- one-time staging of W_ih slice into LDS ----
  for (int i = tid; i < 16 * (V_ / 4); i += NTH) {   // 1024 float4s
    int rl = i >> 6;
    int kq = i & 63;
    int rr = (rl >> 2) * H_ + wg * 4 + (rl & 3);
    *(float4*)&Wis[rl][kq * 4] = *(const float4*)&W_ih[(size_t)rr * V_ + kq * 4];
  }
  if (tid < 16) {
    int rr = (tid >> 2) * H_ + wg * 4 + (tid & 3);
    bias_s[tid] = b_ih[rr] + b_hh[rr];
  }
  if (tid < 32) c_s[tid >> 3][tid & 7] = 0.f;

  int   pending = 0, chunk = 0, ptau = 0;
  float wg_loss = 0.f;

  // one 1/32 slice of the fused output-projection + CE for position (b_g, ptau)
  auto do_chunk = [&]() {
    const int v_loc = tid >> 5, lane32 = tid & 31;
    const int vg = chunk * 8 + v_loc;
    const float* wrow = &W1[(size_t)vg * H_];
    float4 la = make_float4(0.f, 0.f, 0.f, 0.f);
    #pragma unroll
    for (int j = 0; j < 8; ++j) {
      const int k0 = lane32 * 4 + j * 128;
      const float4 w4 = *(const float4*)&wrow[k0];
      const float4 h4 = *(const float4*)&stash[k0];
      la.x = fmaf(w4.x, h4.x, la.x);
      la.y = fmaf(w4.y, h4.y, la.y);
      la.z = fmaf(w4.z, h4.z, la.z);
      la.w = fmaf(w4.w, h4.w, la.w);
    }
    float l = (la.x + la.y) + (la.z + la.w);
    #pragma unroll
    for (int m = 1; m < 32; m <<= 1) l += __shfl_xor(l, m, 64);
    if (lane32 == 0) logits_s[vg] = l + b1[vg];
    chunk++;
    if (chunk == 32) {          // all 256 logits ready -> softmax + NLL
      __syncthreads();
      if (tid < 64) {
        float mx = -3.4e38f;
        #pragma unroll
        for (int i2 = 0; i2 < 4; ++i2) mx = fmaxf(mx, logits_s[tid * 4 + i2]);
        #pragma unroll
        for (int m = 1; m < 64; m <<= 1) mx = fmaxf(mx, __shfl_xor(mx, m, 64));
        float se = 0.f;
        #pragma unroll
        for (int i2 = 0; i2 < 4; ++i2) se += __expf(logits_s[tid * 4 + i2] - mx);
        #pragma unroll
        for (int m = 1; m < 64; m <<= 1) se += __shfl_xor(se, m, 64);
        if (tid == 0) {
          const float ly = logits_s[ys[b_g * T_ + ptau]];
          wg_loss += -(ly - mx - __logf(se));
        }
      }
      pending = 0;
      chunk = 0;
      __syncthreads();
    }
  };

  __syncthreads();

  for (int t = 0; t < T_; ++t) {
    // ---- stage h(t-1) from global double-buffer (agent atomics: cache-bypass) ----
    const float* hb = hg + ((t + 1) & 1) * (B_ * H_);
    #pragma unroll
    for (int i = 0; i < (B_ * H_) / NTH; ++i) {   // 32 coalesced dword loads
      const int idx = i * NTH + tid;
      hstage[idx >> 10][idx & (H_ - 1)] = agload(&hb[idx]);
    }
    if (tid < 8) xbuf[tid] = Xs[tid * T_ + t];
    __syncthreads();

    // ---- gate partial dots: thread (row, seg), register-blocked over 8 batches ----
    float4 acc[8];
    #pragma unroll
    for (int b = 0; b < 8; ++b) acc[b] = make_float4(0.f, 0.f, 0.f, 0.f);
    #pragma unroll
    for (int q = 0; q < 16; ++q) {
      const int k0 = seg * 4 + q * 64;
      const float4 w = wreg[q];
      #pragma unroll
      for (int b = 0; b < 8; ++b) {
        const float4 h4 = *(const float4*)&hstage[b][k0];
        acc[b].x = fmaf(w.x, h4.x, acc[b].x);
        acc[b].y = fmaf(w.y, h4.y, acc[b].y);
        acc[b].z = fmaf(w.z, h4.z, acc[b].z);
        acc[b].w = fmaf(w.w, h4.w, acc[b].w);
      }
    }
    float s[8];
    #pragma unroll
    for (int b = 0; b < 8; ++b) s[b] = (acc[b].x + acc[b].y) + (acc[b].z + acc[b].w);
    #pragma unroll
    for (int m = 1; m < 16; m <<= 1) {
      #pragma unroll
      for (int b = 0; b < 8; ++b) s[b] += __shfl_xor(s[b], m, 64);
    }
    if (seg < 8)   // b = seg: add one-hot input projection + biases
      gates_s[row][seg] = s[seg] + Wis[row][xbuf[seg]] + bias_s[row];
    __syncthreads();

    // ---- c/h update (i,f,g,o at local rows jj, 4+jj, 8+jj, 12+jj) ----
    if (tid < 32) {
      const int jj = tid >> 3, b = tid & 7;
      float iv = gates_s[jj][b],      fv = gates_s[4 + jj][b];
      float gv = gates_s[8 + jj][b],  ov = gates_s[12 + jj][b];
      iv = 1.f / (1.f + __expf(-iv));
      fv = 1.f / (1.f + __expf(-fv));
      gv = tanhf(gv);
      ov = 1.f / (1.f + __expf(-ov));
      const float c = fv * c_s[jj][b] + iv * gv;
      c_s[jj][b] = c;
      const float h = ov * tanhf(c);
      agstore(&hg[(t & 1) * (B_ * H_) + b * H_ + wg * 4 + jj], h);
    }

    // ---- fused-loss slice: independent of h(t), hides under barrier wait ----
    if (pending) do_chunk();

    {
      const int tau = t - 1;   // hstage currently holds h(tau)
      if (tau >= 0 && (tau & 31) == slot && !pending) {
        for (int i = tid; i < H_; i += NTH) stash[i] = hstage[b_g][i];
        pending = 1; chunk = 0; ptau = tau;
      }
    }

    // ---- grid barrier: monotonic counter, agent scope ----
    __syncthreads();   // wave 0 issued the h stores; its vmcnt drains here
    if (tid == 0) {
      __hip_atomic_fetch_add(bar, 1, __ATOMIC_ACQ_REL, __HIP_MEMORY_SCOPE_AGENT);
      const int target = (t + 1) * NWG;
      while (__hip_atomic_load(bar, __ATOMIC_RELAXED, __HIP_MEMORY_SCOPE_AGENT) < target)
        __builtin_amdgcn_s_sleep(1);
    }
    __syncthreads();
  }

  // ---- drain: finish in-flight loss position ----
  while (pending) do_chunk();

  // ---- tau = T-1 (slot 31 only) was never staged inside the loop ----
  if (slot == 31) {
    for (int i = tid; i < H_; i += NTH)
      stash[i] = agload(&hg[((T_ - 1) & 1) * (B_ * H_) + b_g * H_ + i]);
    pending = 1; chunk = 0; ptau = T_ - 1;
    __syncthreads();
    while (pending) do_chunk();
  }

  if (tid == 0) atomicAdd(out, wg_loss * (1.0f / (B_ * T_)));
}

extern "C" void kernel_launch(void* const* d_in, const int* in_sizes, int n_in,
                              void* d_out, int out_size, void* d_ws, size_t ws_size,
                              hipStream_t stream) {
  const int*   Xs   = (const int*)d_in[0];
  const int*   ys   = (const int*)d_in[1];
  // d_in[2] = predict (always 0 in this problem)
  const float* W_ih = (const float*)d_in[3];
  const float* W_hh = (const float*)d_in[4];
  const float* b_ih = (const float*)d_in[5];
  const float* b_hh = (const float*)d_in[6];
  const float* W1   = (const float*)d_in[7];
  const float* b1   = (const float*)d_in[8];
  float* out = (float*)d_out;

  int*   bar = (int*)d_ws;                       // barrier counter
  float* hg  = (float*)((char*)d_ws + 256);      // h double-buffer [2][B][H]

  // replay-safe: zero the accumulator output + barrier/h state every call
  hipMemsetAsync(d_out, 0, sizeof(float) * (size_t)out_size, stream);
  hipMemsetAsync(d_ws, 0, 256 + 2 * B_ * H_ * sizeof(float), stream);

  void* args[] = { (void*)&Xs, (void*)&ys, (void*)&W_ih, (void*)&W_hh,
                   (void*)&b_ih, (void*)&b_hh, (void*)&W1, (void*)&b1,
                   (void*)&out, (void*)&bar, (void*)&hg };
  hipError_t e = hipLaunchCooperativeKernel((const void*)charrnn_lstm, dim3(NWG),
                                            dim3(NTH), args, 0, stream);
  if (e != hipSuccess) {
    // fallback: plain launch. 1 WG/CU, grid == CU count -> co-resident in practice.
    hipLaunchKernelGGL(charrnn_lstm, dim3(NWG), dim3(NTH), 0, stream,
                       Xs, ys, W_ih, W_hh, b_ih, b_hh, W1, b1, out, bar, hg);
  }
}

// Round 3
// 25903.198 us; speedup vs baseline: 1.4143x; 1.4143x over previous
//
#include <hip/hip_runtime.h>

#define H_  1024
#define B_  8
#define T_  2048
#define V_  256
#define NWG 256
#define NTH 256
#define FSTRIDE 32   // ints; 128-B spacing between arrive flags

__device__ __forceinline__ float agload(const float* p) {
  return __hip_atomic_load(p, __ATOMIC_RELAXED, __HIP_MEMORY_SCOPE_AGENT);
}
__device__ __forceinline__ void agstore(float* p, float v) {
  __hip_atomic_store(p, v, __ATOMIC_RELAXED, __HIP_MEMORY_SCOPE_AGENT);
}
__device__ __forceinline__ int agloadi(const int* p) {
  return __hip_atomic_load(p, __ATOMIC_RELAXED, __HIP_MEMORY_SCOPE_AGENT);
}
__device__ __forceinline__ void agstorei(int* p, int v) {
  __hip_atomic_store(p, v, __ATOMIC_RELAXED, __HIP_MEMORY_SCOPE_AGENT);
}

__global__ __launch_bounds__(NTH, 1)
void charrnn_lstm(const int* __restrict__ Xs, const int* __restrict__ ys,
                  const float* __restrict__ W_ih, const float* __restrict__ W_hh,
                  const float* __restrict__ b_ih, const float* __restrict__ b_hh,
                  const float* __restrict__ W1, const float* __restrict__ b1,
                  float* __restrict__ out, int* __restrict__ arrive, float* __restrict__ hg)
{
  // LDS total ~55 KB (<64KB limit; W_hh slice lives in 64 VGPRs/thread).
  __shared__ float hstage[B_][H_];
  __shared__ float Wis[16][V_];
  __shared__ float stash[H_];
  __shared__ float logits_s[V_];
  __shared__ float gates_s[16][8];
  __shared__ float c_s[4][8];
  __shared__ float bias_s[16];
  __shared__ int   xbuf[8];

  const int wg   = blockIdx.x;
  const int tid  = threadIdx.x;
  const int b_g  = wg & 7;    // batch whose loss this WG computes
  const int slot = wg >> 3;   // t%32 slot this WG stashes
  const int row  = tid >> 4;  // 0..15 : local gate-row (gate*4 + jj)
  const int seg  = tid & 15;  // 0..15 : k-segment

  // ---- W_hh slice -> registers: thread (row,seg) needs exactly these 64 floats ----
  const int rg = (row >> 2) * H_ + wg * 4 + (row & 3);   // global W_hh/W_ih row
  float4 wreg[16];
  #pragma unroll
  for (int q = 0; q < 16; ++q)
    wreg[q] = *(const float4*)&W_hh[(size_t)rg * H_ + seg * 4 + q * 64];

  // ---- one-time staging of W_ih slice into LDS ----
  for (int i = tid; i < 16 * (V_ / 4); i += NTH) {   // 1024 float4s
    int rl = i >> 6;
    int kq = i & 63;
    int rr = (rl >> 2) * H_ + wg * 4 + (rl & 3);
    *(float4*)&Wis[rl][kq * 4] = *(const float4*)&W_ih[(size_t)rr * V_ + kq * 4];
  }
  if (tid < 16) {
    int rr = (tid >> 2) * H_ + wg * 4 + (tid & 3);
    bias_s[tid] = b_ih[rr] + b_hh[rr];
  }
  if (tid < 32) c_s[tid >> 3][tid & 7] = 0.f;

  int   pending = 0, chunk = 0, ptau = 0;
  float wg_loss = 0.f;

  // one 1/32 slice of the fused output-projection + CE for position (b_g, ptau)
  auto do_chunk = [&]() {
    const int v_loc = tid >> 5, lane32 = tid & 31;
    const int vg = chunk * 8 + v_loc;
    const float* wrow = &W1[(size_t)vg * H_];
    float4 la = make_float4(0.f, 0.f, 0.f, 0.f);
    #pragma unroll
    for (int j = 0; j < 8; ++j) {
      const int k0 = lane32 * 4 + j * 128;
      const float4 w4 = *(const float4*)&wrow[k0];
      const float4 h4 = *(const float4*)&stash[k0];
      la.x = fmaf(w4.x, h4.x, la.x);
      la.y = fmaf(w4.y, h4.y, la.y);
      la.z = fmaf(w4.z, h4.z, la.z);
      la.w = fmaf(w4.w, h4.w, la.w);
    }
    float l = (la.x + la.y) + (la.z + la.w);
    #pragma unroll
    for (int m = 1; m < 32; m <<= 1) l += __shfl_xor(l, m, 64);
    if (lane32 == 0) logits_s[vg] = l + b1[vg];
    chunk++;
    if (chunk == 32) {          // all 256 logits ready -> softmax + NLL
      __syncthreads();
      if (tid < 64) {
        float mx = -3.4e38f;
        #pragma unroll
        for (int i2 = 0; i2 < 4; ++i2) mx = fmaxf(mx, logits_s[tid * 4 + i2]);
        #pragma unroll
        for (int m = 1; m < 64; m <<= 1) mx = fmaxf(mx, __shfl_xor(mx, m, 64));
        float se = 0.f;
        #pragma unroll
        for (int i2 = 0; i2 < 4; ++i2) se += __expf(logits_s[tid * 4 + i2] - mx);
        #pragma unroll
        for (int m = 1; m < 64; m <<= 1) se += __shfl_xor(se, m, 64);
        if (tid == 0) {
          const float ly = logits_s[ys[b_g * T_ + ptau]];
          wg_loss += -(ly - mx - __logf(se));
        }
      }
      pending = 0;
      chunk = 0;
      __syncthreads();
    }
  };

  __syncthreads();

  for (int t = 0; t < T_; ++t) {
    // ---- stage h(t-1) from global double-buffer (agent atomics: cache-bypass) ----
    const float* hb = hg + ((t + 1) & 1) * (B_ * H_);
    #pragma unroll
    for (int i = 0; i < (B_ * H_) / NTH; ++i) {   // 32 coalesced dword loads
      const int idx = i * NTH + tid;
      hstage[idx >> 10][idx & (H_ - 1)] = agload(&hb[idx]);
    }
    if (tid < 8) xbuf[tid] = Xs[tid * T_ + t];
    __syncthreads();

    // ---- gate partial dots: thread (row, seg), register-blocked over 8 batches ----
    float4 acc[8];
    #pragma unroll
    for (int b = 0; b < 8; ++b) acc[b] = make_float4(0.f, 0.f, 0.f, 0.f);
    #pragma unroll
    for (int q = 0; q < 16; ++q) {
      const int k0 = seg * 4 + q * 64;
      const float4 w = wreg[q];
      #pragma unroll
      for (int b = 0; b < 8; ++b) {
        const float4 h4 = *(const float4*)&hstage[b][k0];
        acc[b].x = fmaf(w.x, h4.x, acc[b].x);
        acc[b].y = fmaf(w.y, h4.y, acc[b].y);
        acc[b].z = fmaf(w.z, h4.z, acc[b].z);
        acc[b].w = fmaf(w.w, h4.w, acc[b].w);
      }
    }
    float s[8];
    #pragma unroll
    for (int b = 0; b < 8; ++b) s[b] = (acc[b].x + acc[b].y) + (acc[b].z + acc[b].w);
    #pragma unroll
    for (int m = 1; m < 16; m <<= 1) {
      #pragma unroll
      for (int b = 0; b < 8; ++b) s[b] += __shfl_xor(s[b], m, 64);
    }
    if (seg < 8)   // b = seg: add one-hot input projection + biases
      gates_s[row][seg] = s[seg] + Wis[row][xbuf[seg]] + bias_s[row];
    __syncthreads();

    // ---- c/h update (i,f,g,o at local rows jj, 4+jj, 8+jj, 12+jj) ----
    if (tid < 32) {
      const int jj = tid >> 3, b = tid & 7;
      float iv = gates_s[jj][b],      fv = gates_s[4 + jj][b];
      float gv = gates_s[8 + jj][b],  ov = gates_s[12 + jj][b];
      iv = 1.f / (1.f + __expf(-iv));
      fv = 1.f / (1.f + __expf(-fv));
      gv = tanhf(gv);
      ov = 1.f / (1.f + __expf(-ov));
      const float c = fv * c_s[jj][b] + iv * gv;
      c_s[jj][b] = c;
      const float h = ov * tanhf(c);
      agstore(&hg[(t & 1) * (B_ * H_) + b * H_ + wg * 4 + jj], h);
    }

    // ---- fused-loss slice: independent of h(t), hides under barrier wait ----
    if (pending) do_chunk();

    {
      const int tau = t - 1;   // hstage currently holds h(tau)
      if (tau >= 0 && (tau & 31) == slot && !pending) {
        for (int i = tid; i < H_; i += NTH) stash[i] = hstage[b_g][i];
        pending = 1; chunk = 0; ptau = tau;
      }
    }

    // ---- grid barrier: contention-free flag array ----
    // __syncthreads drains vmcnt(0) for every wave -> all h stores of this WG
    // are complete at the coherence point before the arrive-flag store.
    __syncthreads();
    if (tid == 0) agstorei(&arrive[wg * FSTRIDE], t + 1);
    // NTH==NWG: thread tid polls WG tid's flag; all flags covered in parallel,
    // no RMWs, no shared hot line.
    while (agloadi(&arrive[tid * FSTRIDE]) <= t)
      __builtin_amdgcn_s_sleep(1);
    __syncthreads();   // WG-collective: all 256 flags seen before anyone reads h
  }

  // ---- drain: finish in-flight loss position ----
  while (pending) do_chunk();

  // ---- tau = T-1 (slot 31 only) was never staged inside the loop ----
  if (slot == 31) {
    for (int i = tid; i < H_; i += NTH)
      stash[i] = agload(&hg[((T_ - 1) & 1) * (B_ * H_) + b_g * H_ + i]);
    pending = 1; chunk = 0; ptau = T_ - 1;
    __syncthreads();
    while (pending) do_chunk();
  }

  if (tid == 0) atomicAdd(out, wg_loss * (1.0f / (B_ * T_)));
}

extern "C" void kernel_launch(void* const* d_in, const int* in_sizes, int n_in,
                              void* d_out, int out_size, void* d_ws, size_t ws_size,
                              hipStream_t stream) {
  const int*   Xs   = (const int*)d_in[0];
  const int*   ys   = (const int*)d_in[1];
  // d_in[2] = predict (always 0 in this problem)
  const float* W_ih = (const float*)d_in[3];
  const float* W_hh = (const float*)d_in[4];
  const float* b_ih = (const float*)d_in[5];
  const float* b_hh = (const float*)d_in[6];
  const float* W1   = (const float*)d_in[7];
  const float* b1   = (const float*)d_in[8];
  float* out = (float*)d_out;

  int*   arrive = (int*)d_ws;                                  // [NWG*FSTRIDE]
  float* hg     = (float*)((char*)d_ws + NWG * FSTRIDE * 4);   // h dbuf [2][B][H]

  // replay-safe: zero the accumulator output + barrier/h state every call
  hipMemsetAsync(d_out, 0, sizeof(float) * (size_t)out_size, stream);
  hipMemsetAsync(d_ws, 0, NWG * FSTRIDE * 4 + 2 * B_ * H_ * sizeof(float), stream);

  void* args[] = { (void*)&Xs, (void*)&ys, (void*)&W_ih, (void*)&W_hh,
                   (void*)&b_ih, (void*)&b_hh, (void*)&W1, (void*)&b1,
                   (void*)&out, (void*)&arrive, (void*)&hg };
  hipError_t e = hipLaunchCooperativeKernel((const void*)charrnn_lstm, dim3(NWG),
                                            dim3(NTH), args, 0, stream);
  if (e != hipSuccess) {
    // fallback: plain launch. 1 WG/CU, grid == CU count -> co-resident in practice.
    hipLaunchKernelGGL(charrnn_lstm, dim3(NWG), dim3(NTH), 0, stream,
                       Xs, ys, W_ih, W_hh, b_ih, b_hh, W1, b1, out, arrive, hg);
  }
}

// Round 4
// 9916.317 us; speedup vs baseline: 3.6945x; 2.6122x over previous
//
#include <hip/hip_runtime.h>

#define H_  1024
#define B_  8
#define T_  2048
#define V_  256
#define NWG 256
#define NTH 256

__device__ __forceinline__ unsigned agloadu(const unsigned* p) {
  return __hip_atomic_load(p, __ATOMIC_RELAXED, __HIP_MEMORY_SCOPE_AGENT);
}
__device__ __forceinline__ void agstoreu(unsigned* p, unsigned v) {
  __hip_atomic_store(p, v, __ATOMIC_RELAXED, __HIP_MEMORY_SCOPE_AGENT);
}
// h transported as tagged word: [31:16] = bf16(h) (RNE), [15:0] = step tag
__device__ __forceinline__ unsigned f2bf_hi(float f) {
  unsigned u = __builtin_bit_cast(unsigned, f);
  return (u + 0x7fffu + ((u >> 16) & 1u)) & 0xffff0000u;
}
__device__ __forceinline__ float bf_hi2f(unsigned w) {
  return __builtin_bit_cast(float, w & 0xffff0000u);
}

__global__ __launch_bounds__(NTH, 1)
void charrnn_lstm(const int* __restrict__ Xs, const int* __restrict__ ys,
                  const float* __restrict__ W_ih, const float* __restrict__ W_hh,
                  const float* __restrict__ b_ih, const float* __restrict__ b_hh,
                  const float* __restrict__ W1, const float* __restrict__ b1,
                  float* __restrict__ out, unsigned* __restrict__ hgw)
{
  // LDS ~56 KB (<64KB). W_hh slice in 64 VGPRs/thread.
  __shared__ float hstage[B_][H_];
  __shared__ float Wis[16][V_];
  __shared__ float stash[H_];
  __shared__ float logits_s[V_];
  __shared__ float gates_s[16][8];
  __shared__ float c_s[4][8];
  __shared__ float bias_s[16];
  __shared__ int   xw[8][32];      // 32-step window of Xs

  const int wg   = blockIdx.x;
  const int tid  = threadIdx.x;
  const int b_g  = wg & 7;    // batch whose loss this WG computes
  const int slot = wg >> 3;   // t%32 slot this WG stashes
  const int row  = tid >> 4;  // 0..15 : local gate-row (gate*4 + jj)
  const int seg  = tid & 15;  // 0..15 : k-segment

  // ---- W_hh slice -> registers ----
  const int rg = (row >> 2) * H_ + wg * 4 + (row & 3);
  float4 wreg[16];
  #pragma unroll
  for (int q = 0; q < 16; ++q)
    wreg[q] = *(const float4*)&W_hh[(size_t)rg * H_ + seg * 4 + q * 64];

  // ---- one-time staging of W_ih slice into LDS ----
  for (int i = tid; i < 16 * (V_ / 4); i += NTH) {
    int rl = i >> 6;
    int kq = i & 63;
    int rr = (rl >> 2) * H_ + wg * 4 + (rl & 3);
    *(float4*)&Wis[rl][kq * 4] = *(const float4*)&W_ih[(size_t)rr * V_ + kq * 4];
  }
  if (tid < 16) {
    int rr = (tid >> 2) * H_ + wg * 4 + (tid & 3);
    bias_s[tid] = b_ih[rr] + b_hh[rr];
  }
  if (tid < 32) c_s[tid >> 3][tid & 7] = 0.f;

  int   pending = 0, chunk = 0, ptau = 0;
  float wg_loss = 0.f;

  auto do_chunk = [&]() {   // 1/32 slice of output-projection + CE for (b_g, ptau)
    const int v_loc = tid >> 5, lane32 = tid & 31;
    const int vg = chunk * 8 + v_loc;
    const float* wrow = &W1[(size_t)vg * H_];
    float4 la = make_float4(0.f, 0.f, 0.f, 0.f);
    #pragma unroll
    for (int j = 0; j < 8; ++j) {
      const int k0 = lane32 * 4 + j * 128;
      const float4 w4 = *(const float4*)&wrow[k0];
      const float4 h4 = *(const float4*)&stash[k0];
      la.x = fmaf(w4.x, h4.x, la.x);
      la.y = fmaf(w4.y, h4.y, la.y);
      la.z = fmaf(w4.z, h4.z, la.z);
      la.w = fmaf(w4.w, h4.w, la.w);
    }
    float l = (la.x + la.y) + (la.z + la.w);
    #pragma unroll
    for (int m = 1; m < 32; m <<= 1) l += __shfl_xor(l, m, 64);
    if (lane32 == 0) logits_s[vg] = l + b1[vg];
    chunk++;
    if (chunk == 32) {
      __syncthreads();
      if (tid < 64) {
        float mx = -3.4e38f;
        #pragma unroll
        for (int i2 = 0; i2 < 4; ++i2) mx = fmaxf(mx, logits_s[tid * 4 + i2]);
        #pragma unroll
        for (int m = 1; m < 64; m <<= 1) mx = fmaxf(mx, __shfl_xor(mx, m, 64));
        float se = 0.f;
        #pragma unroll
        for (int i2 = 0; i2 < 4; ++i2) se += __expf(logits_s[tid * 4 + i2] - mx);
        #pragma unroll
        for (int m = 1; m < 64; m <<= 1) se += __shfl_xor(se, m, 64);
        if (tid == 0) {
          const float ly = logits_s[ys[b_g * T_ + ptau]];
          wg_loss += -(ly - mx - __logf(se));
        }
      }
      pending = 0;
      chunk = 0;
      __syncthreads();
    }
  };

  __syncthreads();

  for (int t = 0; t < T_; ++t) {
    // ---- 1. tag-poll stage of h(t-1): single L3 round trip, no barrier ----
    const unsigned* hb = hgw + (size_t)((t + 1) & 1) * (B_ * H_);
    const unsigned tag = (unsigned)t;
    unsigned v[32];
    for (;;) {
      bool ok = true;
      #pragma unroll
      for (int i = 0; i < 32; ++i) v[i] = agloadu(&hb[i * NTH + tid]);
      #pragma unroll
      for (int i = 0; i < 32; ++i) ok &= ((v[i] & 0xffffu) == tag);
      if (ok) break;
      __builtin_amdgcn_s_sleep(1);
    }
    #pragma unroll
    for (int i = 0; i < 32; ++i) {
      const int idx = i * NTH + tid;
      hstage[idx >> 10][idx & (H_ - 1)] = bf_hi2f(v[i]);
    }
    if ((t & 31) == 0) {   // refresh 32-step Xs window (one load/thread)
      const int b = tid >> 5, tt = t + (tid & 31);
      xw[b][tid & 31] = (tt < T_) ? Xs[b * T_ + tt] : 0;
    }
    __syncthreads();

    // ---- 2. gate partial dots ----
    float4 acc[8];
    #pragma unroll
    for (int b = 0; b < 8; ++b) acc[b] = make_float4(0.f, 0.f, 0.f, 0.f);
    #pragma unroll
    for (int q = 0; q < 16; ++q) {
      const int k0 = seg * 4 + q * 64;
      const float4 w = wreg[q];
      #pragma unroll
      for (int b = 0; b < 8; ++b) {
        const float4 h4 = *(const float4*)&hstage[b][k0];
        acc[b].x = fmaf(w.x, h4.x, acc[b].x);
        acc[b].y = fmaf(w.y, h4.y, acc[b].y);
        acc[b].z = fmaf(w.z, h4.z, acc[b].z);
        acc[b].w = fmaf(w.w, h4.w, acc[b].w);
      }
    }
    float s[8];
    #pragma unroll
    for (int b = 0; b < 8; ++b) s[b] = (acc[b].x + acc[b].y) + (acc[b].z + acc[b].w);
    #pragma unroll
    for (int m = 1; m < 16; m <<= 1) {
      #pragma unroll
      for (int b = 0; b < 8; ++b) s[b] += __shfl_xor(s[b], m, 64);
    }
    if (seg < 8)
      gates_s[row][seg] = s[seg] + Wis[row][xw[seg][t & 31]] + bias_s[row];
    __syncthreads();

    // ---- 3. c/h update + tagged store (fire-and-forget, relaxed) ----
    if (tid < 32) {
      const int jj = tid >> 3, b = tid & 7;
      float iv = gates_s[jj][b],      fv = gates_s[4 + jj][b];
      float gv = gates_s[8 + jj][b],  ov = gates_s[12 + jj][b];
      iv = 1.f / (1.f + __expf(-iv));
      fv = 1.f / (1.f + __expf(-fv));
      gv = tanhf(gv);
      ov = 1.f / (1.f + __expf(-ov));
      const float c = fv * c_s[jj][b] + iv * gv;
      c_s[jj][b] = c;
      const float h = ov * tanhf(c);
      agstoreu(&hgw[(size_t)(t & 1) * (B_ * H_) + b * H_ + wg * 4 + jj],
               f2bf_hi(h) | (unsigned)(t + 1));
    }

    // ---- 4. stash h(tau) for this WG's loss position ----
    const int tau = t - 1;   // hstage holds h(t-1)
    const bool newst = (tau >= 0 && (tau & 31) == slot && !pending);
    if (newst) {
      for (int i = tid; i < H_; i += NTH) stash[i] = hstage[b_g][i];
    }
    if (newst) { pending = 1; chunk = 0; ptau = tau; }
    __syncthreads();   // stash ready; also fences hstage reuse vs next stage

    // ---- 5. fused-loss slice: hides under h-store visibility window ----
    if (pending) do_chunk();
  }

  // ---- drain in-flight loss position ----
  while (pending) do_chunk();

  // ---- tau = T-1 (slot 31): poll-decode final h for batch b_g ----
  if (slot == 31) {
    const unsigned* hb = hgw + (size_t)((T_ - 1) & 1) * (B_ * H_);
    for (int k = 0; k < H_ / NTH; ++k) {
      const int i = k * NTH + tid;
      unsigned w;
      do { w = agloadu(&hb[b_g * H_ + i]); } while ((w & 0xffffu) != (unsigned)T_);
      stash[i] = bf_hi2f(w);
    }
    pending = 1; chunk = 0; ptau = T_ - 1;
    __syncthreads();
    while (pending) do_chunk();
  }

  if (tid == 0) atomicAdd(out, wg_loss * (1.0f / (B_ * T_)));
}

extern "C" void kernel_launch(void* const* d_in, const int* in_sizes, int n_in,
                              void* d_out, int out_size, void* d_ws, size_t ws_size,
                              hipStream_t stream) {
  const int*   Xs   = (const int*)d_in[0];
  const int*   ys   = (const int*)d_in[1];
  // d_in[2] = predict (always 0)
  const float* W_ih = (const float*)d_in[3];
  const float* W_hh = (const float*)d_in[4];
  const float* b_ih = (const float*)d_in[5];
  const float* b_hh = (const float*)d_in[6];
  const float* W1   = (const float*)d_in[7];
  const float* b1   = (const float*)d_in[8];
  float* out = (float*)d_out;

  unsigned* hgw = (unsigned*)d_ws;   // [2][B*H] tagged h words

  // replay-safe: zeroed buffer == h(-1)=0 with tag 0; zero loss accumulator
  hipMemsetAsync(d_out, 0, sizeof(float) * (size_t)out_size, stream);
  hipMemsetAsync(d_ws, 0, 2 * B_ * H_ * sizeof(unsigned), stream);

  void* args[] = { (void*)&Xs, (void*)&ys, (void*)&W_ih, (void*)&W_hh,
                   (void*)&b_ih, (void*)&b_hh, (void*)&W1, (void*)&b1,
                   (void*)&out, (void*)&hgw };
  hipError_t e = hipLaunchCooperativeKernel((const void*)charrnn_lstm, dim3(NWG),
                                            dim3(NTH), args, 0, stream);
  if (e != hipSuccess) {
    hipLaunchKernelGGL(charrnn_lstm, dim3(NWG), dim3(NTH), 0, stream,
                       Xs, ys, W_ih, W_hh, b_ih, b_hh, W1, b1, out, hgw);
  }
}